// Round 3
// baseline (571.825 us; speedup 1.0000x reference)
//
#include <hip/hip_runtime.h>

// Unpool_LS: per 2x2 block (L=4) per channel:
//   v[l] = x0[b, 2i+p, 2j+q, c], l = p*2+q
//   sort desc -> sv; cs[k] = cumsum(sv); avg[k] = (cs[k]+x1)/(k+2)
//   repl = max(avg), k = first argmax (strict > keeps first, matches jnp.argmax)
//   mask[l] = (stable descending rank of v[l]) <= k
//   out0[l] = mask ? repl : v[l];  out1 = repl;  out2[l] = mask ? (k+1)/(k+2) : 1
//
// Memory-bound: 160 MB read + 288 MB write = 448 MB -> ~71 us floor @ 6.3 TB/s.
// R3: fix nontemporal builtin types (ext_vector_type instead of HIP_vector_type).
// 8 channels/thread; only /3 and /5 remain IEEE divides (argmax tie-exactness);
// frac via compile-time-exact constants; min/max sort network; nt streaming.

namespace {
constexpr int NB = 8;
constexpr int H  = 256;
constexpr int W  = 256;
constexpr int C  = 64;
constexpr int hh = H / 2;   // 128
constexpr int ww = W / 2;   // 128
constexpr long long N0 = (long long)NB * H * W * C;    // 33554432 (out0)
constexpr long long N1 = (long long)NB * hh * ww * C;  //  8388608 (repl)
}

typedef float v4f __attribute__((ext_vector_type(4)));  // native vector: ok for nontemporal builtins

__device__ __forceinline__ void solve1(float a0, float a1, float a2, float a3,
                                       float x1e,
                                       float out_a[4], float out_f[4], float& repl)
{
    // descending 5-comparator sort network, values only (inputs NaN-free)
    const float b0 = fmaxf(a0, a1), b1 = fminf(a0, a1);
    const float b2 = fmaxf(a2, a3), b3 = fminf(a2, a3);
    const float c0 = fmaxf(b0, b2), c2 = fminf(b0, b2);
    const float c1 = fmaxf(b1, b3), c3 = fminf(b1, b3);
    const float d1 = fmaxf(c1, c2), d2 = fminf(c1, c2);
    // sorted desc: c0, d1, d2, c3

    // cumsum (sequential rounding matches jnp.cumsum), then +x1, then /denom.
    // /2 and /4 as *0.5f / *0.25f are bit-exact; /3 and /5 stay IEEE divides
    // so argmax near-ties round identically to the reference.
    const float cs0 = c0;
    const float cs1 = cs0 + d1;
    const float cs2 = cs1 + d2;
    const float cs3 = cs2 + c3;
    const float q0 = (cs0 + x1e) * 0.5f;
    const float q1 = (cs1 + x1e) / 3.0f;
    const float q2 = (cs2 + x1e) * 0.25f;
    const float q3 = (cs3 + x1e) / 5.0f;

    float best = q0; int k = 0;
    if (q1 > best) { best = q1; k = 1; }
    if (q2 > best) { best = q2; k = 2; }
    if (q3 > best) { best = q3; k = 3; }

    // (k+1)/(k+2) for k in {0..3}: compile-time IEEE division -> identical
    // rounded constants {0.5, 0.66666669, 0.75, 0.80000001}
    const float frac = (k == 0) ? 0.5f
                     : (k == 1) ? (2.0f / 3.0f)
                     : (k == 2) ? 0.75f
                     : (4.0f / 5.0f);

    const float va[4] = {a0, a1, a2, a3};
#pragma unroll
    for (int l = 0; l < 4; ++l) {
        const float vl = va[l];
        int rank = 0;
#pragma unroll
        for (int m = 0; m < 4; ++m) {
            const float vm = va[m];
            rank += (vm > vl) ? 1 : ((vm == vl && m < l) ? 1 : 0);
        }
        const bool sel = (rank <= k);
        out_a[l] = sel ? best : vl;
        out_f[l] = sel ? frac : 1.0f;
    }
    repl = best;
}

__global__ __launch_bounds__(256)
void unpool_ls_kernel(const float* __restrict__ x0, const float* __restrict__ x1,
                      float* __restrict__ out0, float* __restrict__ out1,
                      float* __restrict__ out2)
{
    const int t  = blockIdx.x * blockDim.x + threadIdx.x;
    // total threads = NB*hh*ww*(C/8) = 1,048,576; 8 channels per thread
    const int c8 = t & 7;                // which 8-channel group
    const int j  = (t >> 3) & (ww - 1);
    const int i  = (t >> 10) & (hh - 1);
    const int b  = t >> 17;

    const size_t rowS  = (size_t)W * C;
    const size_t base0 = ((size_t)((b * H + 2 * i) * W + 2 * j)) * C + c8 * 8;
    const size_t baseP = ((size_t)((b * hh + i) * ww + j)) * C + c8 * 8;

    // Issue ALL loads up front (10 nt loads in flight per thread)
    v4f L[2][4];   // [group][block position l]
    v4f P[2];
#pragma unroll
    for (int g = 0; g < 2; ++g) {
        L[g][0] = __builtin_nontemporal_load((const v4f*)(x0 + base0 + 4 * g));
        L[g][1] = __builtin_nontemporal_load((const v4f*)(x0 + base0 + C + 4 * g));
        L[g][2] = __builtin_nontemporal_load((const v4f*)(x0 + base0 + rowS + 4 * g));
        L[g][3] = __builtin_nontemporal_load((const v4f*)(x0 + base0 + rowS + C + 4 * g));
        P[g]    = __builtin_nontemporal_load((const v4f*)(x1 + baseP + 4 * g));
    }

#pragma unroll
    for (int g = 0; g < 2; ++g) {
        v4f oa[4], of4[4], orp;
#pragma unroll
        for (int e = 0; e < 4; ++e) {
            float out_a[4], out_f[4], repl;
            solve1(L[g][0][e], L[g][1][e], L[g][2][e], L[g][3][e],
                   P[g][e], out_a, out_f, repl);
#pragma unroll
            for (int l = 0; l < 4; ++l) {
                oa[l][e]  = out_a[l];
                of4[l][e] = out_f[l];
            }
            orp[e] = repl;
        }
        __builtin_nontemporal_store(oa[0], (v4f*)(out0 + base0 + 4 * g));
        __builtin_nontemporal_store(oa[1], (v4f*)(out0 + base0 + C + 4 * g));
        __builtin_nontemporal_store(oa[2], (v4f*)(out0 + base0 + rowS + 4 * g));
        __builtin_nontemporal_store(oa[3], (v4f*)(out0 + base0 + rowS + C + 4 * g));
        __builtin_nontemporal_store(orp,   (v4f*)(out1 + baseP + 4 * g));
        __builtin_nontemporal_store(of4[0], (v4f*)(out2 + base0 + 4 * g));
        __builtin_nontemporal_store(of4[1], (v4f*)(out2 + base0 + C + 4 * g));
        __builtin_nontemporal_store(of4[2], (v4f*)(out2 + base0 + rowS + 4 * g));
        __builtin_nontemporal_store(of4[3], (v4f*)(out2 + base0 + rowS + C + 4 * g));
    }
}

extern "C" void kernel_launch(void* const* d_in, const int* in_sizes, int n_in,
                              void* d_out, int out_size, void* d_ws, size_t ws_size,
                              hipStream_t stream) {
    const float* x0 = (const float*)d_in[0];
    const float* x1 = (const float*)d_in[1];
    float* out0 = (float*)d_out;          // [8,256,256,64]
    float* out1 = out0 + N0;              // [8,128,128,64]
    float* out2 = out1 + N1;              // [8,256,256,64]

    const int total = NB * hh * ww * (C / 8);   // 1,048,576
    const int block = 256;
    const int grid  = total / block;            // 4096
    hipLaunchKernelGGL(unpool_ls_kernel, dim3(grid), dim3(block), 0, stream,
                       x0, x1, out0, out1, out2);
}

// Round 4
// 399.507 us; speedup vs baseline: 1.4313x; 1.4313x over previous
//
#include <hip/hip_runtime.h>

// Unpool_LS: per 2x2 block (L=4) per channel:
//   v[l] = x0[b, 2i+p, 2j+q, c], l = p*2+q
//   sort desc -> sv; cs[k] = cumsum(sv); avg[k] = (cs[k]+x1)/(k+2)
//   repl = max(avg), k = first argmax (strict > keeps first, matches jnp.argmax)
//   mask[l] = (stable descending rank of v[l]) <= k
//   out0[l] = mask ? repl : v[l];  out1 = repl;  out2[l] = mask ? (k+1)/(k+2) : 1
//
// Memory-bound: 160 MB read + 288 MB write = 448 MB -> ~71 us floor @ 6.3 TB/s.
// R4: REVERT to 4-ch/thread mapping. R3's 8-ch layout made each store
// instruction write 16B-at-32B-stride (half of every sector) -> nt stores
// flushed half-lines -> WRITE_SIZE 582 MB = 2x ideal. With 4 ch/thread,
// lane c4 writes bytes [c4*16, c4*16+16): every wave store instruction is
// 1 KiB contiguous, so nt streaming is safe. Keep min/max sort network,
// 2 IEEE divides only, constant frac select.

namespace {
constexpr int NB = 8;
constexpr int H  = 256;
constexpr int W  = 256;
constexpr int C  = 64;
constexpr int hh = H / 2;   // 128
constexpr int ww = W / 2;   // 128
constexpr long long N0 = (long long)NB * H * W * C;    // 33554432 (out0)
constexpr long long N1 = (long long)NB * hh * ww * C;  //  8388608 (repl)
}

typedef float v4f __attribute__((ext_vector_type(4)));  // native vector: ok for nontemporal builtins

__device__ __forceinline__ void solve1(float a0, float a1, float a2, float a3,
                                       float x1e,
                                       float out_a[4], float out_f[4], float& repl)
{
    // descending 5-comparator sort network, values only (inputs NaN-free)
    const float b0 = fmaxf(a0, a1), b1 = fminf(a0, a1);
    const float b2 = fmaxf(a2, a3), b3 = fminf(a2, a3);
    const float c0 = fmaxf(b0, b2), c2 = fminf(b0, b2);
    const float c1 = fmaxf(b1, b3), c3 = fminf(b1, b3);
    const float d1 = fmaxf(c1, c2), d2 = fminf(c1, c2);
    // sorted desc: c0, d1, d2, c3

    // cumsum (sequential rounding matches jnp.cumsum), then +x1, then /denom.
    // /2 and /4 as *0.5f / *0.25f are bit-exact; /3 and /5 stay IEEE divides
    // so argmax near-ties round identically to the reference.
    const float cs0 = c0;
    const float cs1 = cs0 + d1;
    const float cs2 = cs1 + d2;
    const float cs3 = cs2 + c3;
    const float q0 = (cs0 + x1e) * 0.5f;
    const float q1 = (cs1 + x1e) / 3.0f;
    const float q2 = (cs2 + x1e) * 0.25f;
    const float q3 = (cs3 + x1e) / 5.0f;

    float best = q0; int k = 0;
    if (q1 > best) { best = q1; k = 1; }
    if (q2 > best) { best = q2; k = 2; }
    if (q3 > best) { best = q3; k = 3; }

    // (k+1)/(k+2) for k in {0..3}: compile-time IEEE division -> identical
    // rounded constants {0.5, 0.66666669, 0.75, 0.80000001}
    const float frac = (k == 0) ? 0.5f
                     : (k == 1) ? (2.0f / 3.0f)
                     : (k == 2) ? 0.75f
                     : (4.0f / 5.0f);

    const float va[4] = {a0, a1, a2, a3};
#pragma unroll
    for (int l = 0; l < 4; ++l) {
        const float vl = va[l];
        int rank = 0;
#pragma unroll
        for (int m = 0; m < 4; ++m) {
            const float vm = va[m];
            rank += (vm > vl) ? 1 : ((vm == vl && m < l) ? 1 : 0);
        }
        const bool sel = (rank <= k);
        out_a[l] = sel ? best : vl;
        out_f[l] = sel ? frac : 1.0f;
    }
    repl = best;
}

__global__ __launch_bounds__(256)
void unpool_ls_kernel(const float* __restrict__ x0, const float* __restrict__ x1,
                      float* __restrict__ out0, float* __restrict__ out1,
                      float* __restrict__ out2)
{
    const int t  = blockIdx.x * blockDim.x + threadIdx.x;
    // total threads = NB*hh*ww*(C/4) = 2,097,152; 4 channels per thread.
    // Lane c4 owns bytes [c4*16, c4*16+16) of each pixel's 256 B channel row:
    // every wave memory instruction is contiguous (16 lanes x 16 B per pixel).
    const int c4 = t & 15;
    const int j  = (t >> 4) & (ww - 1);
    const int i  = (t >> 11) & (hh - 1);
    const int b  = t >> 18;

    const size_t rowS  = (size_t)W * C;
    const size_t base0 = ((size_t)((b * H + 2 * i) * W + 2 * j)) * C + c4 * 4;
    const size_t baseP = ((size_t)((b * hh + i) * ww + j)) * C + c4 * 4;

    // All 5 nt loads issued up front
    const v4f v00 = __builtin_nontemporal_load((const v4f*)(x0 + base0));
    const v4f v01 = __builtin_nontemporal_load((const v4f*)(x0 + base0 + C));
    const v4f v10 = __builtin_nontemporal_load((const v4f*)(x0 + base0 + rowS));
    const v4f v11 = __builtin_nontemporal_load((const v4f*)(x0 + base0 + rowS + C));
    const v4f pv  = __builtin_nontemporal_load((const v4f*)(x1 + baseP));

    v4f oa[4], of4[4], orp;
#pragma unroll
    for (int e = 0; e < 4; ++e) {
        float out_a[4], out_f[4], repl;
        solve1(v00[e], v01[e], v10[e], v11[e], pv[e], out_a, out_f, repl);
#pragma unroll
        for (int l = 0; l < 4; ++l) {
            oa[l][e]  = out_a[l];
            of4[l][e] = out_f[l];
        }
        orp[e] = repl;
    }

    __builtin_nontemporal_store(oa[0], (v4f*)(out0 + base0));
    __builtin_nontemporal_store(oa[1], (v4f*)(out0 + base0 + C));
    __builtin_nontemporal_store(oa[2], (v4f*)(out0 + base0 + rowS));
    __builtin_nontemporal_store(oa[3], (v4f*)(out0 + base0 + rowS + C));
    __builtin_nontemporal_store(orp,   (v4f*)(out1 + baseP));
    __builtin_nontemporal_store(of4[0], (v4f*)(out2 + base0));
    __builtin_nontemporal_store(of4[1], (v4f*)(out2 + base0 + C));
    __builtin_nontemporal_store(of4[2], (v4f*)(out2 + base0 + rowS));
    __builtin_nontemporal_store(of4[3], (v4f*)(out2 + base0 + rowS + C));
}

extern "C" void kernel_launch(void* const* d_in, const int* in_sizes, int n_in,
                              void* d_out, int out_size, void* d_ws, size_t ws_size,
                              hipStream_t stream) {
    const float* x0 = (const float*)d_in[0];
    const float* x1 = (const float*)d_in[1];
    float* out0 = (float*)d_out;          // [8,256,256,64]
    float* out1 = out0 + N0;              // [8,128,128,64]
    float* out2 = out1 + N1;              // [8,256,256,64]

    const int total = NB * hh * ww * (C / 4);   // 2,097,152
    const int block = 256;
    const int grid  = total / block;            // 8192
    hipLaunchKernelGGL(unpool_ls_kernel, dim3(grid), dim3(block), 0, stream,
                       x0, x1, out0, out1, out2);
}